// Round 2
// baseline (1371.247 us; speedup 1.0000x reference)
//
#include <hip/hip_runtime.h>

// GCNConv forward: out = segment_sum(vals * (x@W)[cols], rows) + bias
// Round 9: delete the counting sort. sort_gather -> gather_acc:
//  - bucket output tile (32 rows x 128 f32 = 16KB) lives in LDS, init = bias;
//    records streamed ONCE, each = wave-wide 256B h gather + 2 muls +
//    2 native ds_add_f32 per lane. Order-independent -> no histogram pass,
//    no scan, no LDS sort scatter (463K bank conflicts -> ~0), no serial
//    per-row loop. 4 waves round-robin the record list, 8-deep unroll.
//  - BROWS 64->32 (BSHIFT 5): acc 16KB + buf 8KB -> 6 blocks/CU, grid 3125
//    blocks (12.2/CU) -> occupancy cap 75% (was 56%).
//  - fill_xcd: 4 edges/thread -> 4 independent load->atomic->store chains
//    per thread to cover the ~600cy device-atomic latency (VALU was 0.8%).
//
// ws: h[N*128] bf16 | wt[128*264] bf16 | cursors[(NB*8)<<4 +16] int |
//     bcv[NB*8*CAP] int2 | ovf[OVFCAP] int4

typedef __attribute__((ext_vector_type(8))) short short8;
typedef __attribute__((ext_vector_type(4))) float floatx4;
typedef __attribute__((ext_vector_type(2))) int intv2;

#define WT_K 264
#define GM_NODES 128
#define BSHIFT 5              // 32 rows per bucket
#define BROWS 32
#define CAP 128               // records per (xcd,bucket) region; mean 64, 2x headroom
#define CSH 4                 // counters padded to 16 ints = one 64B line
#define OVFCAP 65536
// s_getreg imm: id=20 (HW_REG_XCC_ID), offset=0, size=4 -> (3<<11)|20
#define XCC_GETREG_IMM 6164

static __device__ __forceinline__ uint f2bf(float x) {  // RNE f32->bf16 bits
  uint u = __float_as_uint(x);
  return (u + 0x7fffu + ((u >> 16) & 1u)) >> 16;
}

// ---- W[k][f] f32 -> wt[f][k] bf16 (k padded to WT_K) ----
__global__ __launch_bounds__(256) void conv_w(const float* __restrict__ w,
                                              ushort* __restrict__ wt) {
  const int f = blockIdx.x;
  const int k = threadIdx.x;
  wt[f * WT_K + k] = (ushort)f2bf(w[k * 128 + f]);
}

// ---- GEMM: h^T = W^T x^T via 16x16x32 bf16 MFMA ----
__global__ __launch_bounds__(256) void gemm_mfma(const float* __restrict__ x,
                                                 const ushort* __restrict__ wt,
                                                 ushort* __restrict__ h,
                                                 int n_nodes) {
  __shared__ ushort lw[128 * WT_K];
  __shared__ ushort xa[GM_NODES * 40];
  const int t = threadIdx.x;
  const int lane = t & 63;
  const int wq = t >> 6;
  const int quad = lane >> 4;
  const int l15 = lane & 15;
  const int row0 = blockIdx.x * GM_NODES;

  {
    const uint4* src = (const uint4*)wt;
    uint4* dst = (uint4*)lw;
    for (int i = t; i < (128 * WT_K * 2) / 16; i += 256) dst[i] = src[i];
  }

  floatx4 acc[2][8];
#pragma unroll
  for (int nt = 0; nt < 2; ++nt)
#pragma unroll
    for (int mt = 0; mt < 8; ++mt) acc[nt][mt] = (floatx4){0.f, 0.f, 0.f, 0.f};

  float4 cur[4];
#pragma unroll
  for (int i = 0; i < 4; ++i) {
    const int idx = i * 256 + t;
    const int row = idx >> 3, kq = idx & 7;
    const int gr = row0 + row;
    cur[i] = (gr < n_nodes) ? *(const float4*)&x[(size_t)gr * 256 + kq * 4]
                            : make_float4(0.f, 0.f, 0.f, 0.f);
  }

  for (int kc = 0; kc < 8; ++kc) {
#pragma unroll
    for (int i = 0; i < 4; ++i) {
      const int idx = i * 256 + t;
      const int row = idx >> 3, kq = idx & 7;
      uint2 p;
      p.x = f2bf(cur[i].x) | (f2bf(cur[i].y) << 16);
      p.y = f2bf(cur[i].z) | (f2bf(cur[i].w) << 16);
      *(uint2*)&xa[row * 40 + kq * 4] = p;
    }
    __syncthreads();

    float4 nxt[4];
    if (kc < 7) {
#pragma unroll
      for (int i = 0; i < 4; ++i) {
        const int idx = i * 256 + t;
        const int row = idx >> 3, kq = idx & 7;
        const int gr = row0 + row;
        nxt[i] = (gr < n_nodes)
                     ? *(const float4*)&x[(size_t)gr * 256 + (kc + 1) * 32 + kq * 4]
                     : make_float4(0.f, 0.f, 0.f, 0.f);
      }
    }

    short8 bfr[2];
    bfr[0] = *(const short8*)&xa[(wq * 32 + l15) * 40 + quad * 8];
    bfr[1] = *(const short8*)&xa[(wq * 32 + 16 + l15) * 40 + quad * 8];
#pragma unroll
    for (int mt = 0; mt < 8; ++mt) {
      const short8 afr =
          *(const short8*)&lw[(mt * 16 + l15) * WT_K + kc * 32 + quad * 8];
      acc[0][mt] = __builtin_amdgcn_mfma_f32_16x16x32_bf16(afr, bfr[0],
                                                           acc[0][mt], 0, 0, 0);
      acc[1][mt] = __builtin_amdgcn_mfma_f32_16x16x32_bf16(afr, bfr[1],
                                                           acc[1][mt], 0, 0, 0);
    }
    __syncthreads();
#pragma unroll
    for (int i = 0; i < 4; ++i) cur[i] = nxt[i];
  }

#pragma unroll
  for (int nt = 0; nt < 2; ++nt) {
    const int node = row0 + wq * 32 + nt * 16 + l15;
    if (node < n_nodes) {
#pragma unroll
      for (int mt = 0; mt < 8; ++mt) {
        uint2 p;
        p.x = f2bf(acc[nt][mt][0]) | (f2bf(acc[nt][mt][1]) << 16);
        p.y = f2bf(acc[nt][mt][2]) | (f2bf(acc[nt][mt][3]) << 16);
        *(uint2*)&h[(size_t)node * 128 + mt * 16 + quad * 4] = p;
      }
    }
  }
}

// ---- append edges into (true-XCD, bucket) regions; rowoff packed in col ----
// XCD-major: region = xcd*nb + bucket -> per-XCD contiguous 3.2MB slab.
// Counters padded to one 64B line each. 4 edges/thread for atomic-latency ILP.
__global__ __launch_bounds__(256) void fill_xcd(
    const int* __restrict__ erows, const int* __restrict__ ecols,
    const float* __restrict__ evals, int* __restrict__ cursors,
    int2* __restrict__ bcv, int* __restrict__ ovf_cnt,
    int4* __restrict__ ovf, int n_edges, int nb) {
  const int base = blockIdx.x * 1024 + threadIdx.x;
  const int xcd = (int)(__builtin_amdgcn_s_getreg(XCC_GETREG_IMM)) & 7;
  int rr[4], cc[4];
  float vv[4];
#pragma unroll
  for (int j = 0; j < 4; ++j) {
    const int i = base + j * 256;
    if (i < n_edges) {
      rr[j] = __builtin_nontemporal_load(&erows[i]);
      cc[j] = __builtin_nontemporal_load(&ecols[i]);
      vv[j] = __builtin_nontemporal_load(&evals[i]);
    }
  }
#pragma unroll
  for (int j = 0; j < 4; ++j) {
    const int i = base + j * 256;
    if (i >= n_edges) continue;
    const int reg = xcd * nb + (rr[j] >> BSHIFT);
    const int pos = atomicAdd(&cursors[reg << CSH], 1);
    if (pos < CAP) {
      int2 p;
      p.x = cc[j] | ((rr[j] & (BROWS - 1)) << 17);
      p.y = __float_as_int(vv[j]);
      bcv[(size_t)reg * CAP + pos] = p;
    } else {
      int op = atomicAdd(ovf_cnt, 1);
      if (op < OVFCAP) {
        int4 q; q.x = rr[j]; q.y = cc[j]; q.z = __float_as_int(vv[j]); q.w = 0;
        ovf[op] = q;
      }
    }
  }
}

// ---- fused gather + LDS f32 accumulation (replaces counting sort) ----
// One block per 32-row bucket: acc tile (32x128 f32, init=bias) in LDS;
// stream records once: wave-wide 256B h gather -> 2 muls -> 2 ds_add_f32.
__global__ __launch_bounds__(256) void gather_acc(
    const ushort* __restrict__ h, const int* __restrict__ cursors,
    const int2* __restrict__ bcv, const float* __restrict__ bias,
    float* __restrict__ out, int n_nodes, int nb) {
  __shared__ float acc[BROWS * 128];       // 16 KB
  __shared__ int2 buf[8 * CAP];            // 8 KB staged records
  __shared__ int scnt[8];
  const int b = blockIdx.x;
  const int t = threadIdx.x;
  const int lane = t & 63;
  const int w = t >> 6;

  if (t < 8) scnt[t] = min(cursors[(t * nb + b) << CSH], CAP);
  {  // acc = bias (broadcast per 32-float4 row pattern)
    const float4* b4 = (const float4*)bias;
    float4* a4 = (float4*)acc;
#pragma unroll
    for (int i = t; i < BROWS * 32; i += 256) a4[i] = b4[i & 31];
  }
  __syncthreads();

  // stage all this bucket's records contiguously (single pass over bcv, NT)
  int run = 0;
#pragma unroll
  for (int x = 0; x < 8; ++x) {
    const int n = scnt[x];
    const intv2* src = (const intv2*)&bcv[(size_t)(x * nb + b) * CAP];
    for (int i = t; i < n; i += 256) {
      intv2 rv = __builtin_nontemporal_load(&src[i]);
      int2 rec; rec.x = rv[0]; rec.y = rv[1];
      buf[run + i] = rec;
    }
    run += n;
  }
  __syncthreads();
  const int T = run;

  // process records round-robin across 4 waves, 8-deep unrolled gather
#define GLD(R) (((const uint*)(h + (size_t)((R).x & 0x1FFFF) * 128))[lane])
#define GACC(R, U)                                                    \
  {                                                                   \
    const float v_ = __int_as_float((R).y);                           \
    float* ap_ = acc + (((R).x >> 17) & (BROWS - 1)) * 128 + lane * 2; \
    atomicAdd(ap_, v_ * __uint_as_float((U) << 16));                  \
    atomicAdd(ap_ + 1, v_ * __uint_as_float((U) & 0xffff0000u));      \
  }
  int k = w;
  for (; k + 28 < T; k += 32) {
    const int2 r0 = buf[k], r1 = buf[k + 4], r2 = buf[k + 8], r3 = buf[k + 12];
    const int2 r4 = buf[k + 16], r5 = buf[k + 20], r6 = buf[k + 24],
               r7 = buf[k + 28];
    const uint u0 = GLD(r0), u1 = GLD(r1), u2 = GLD(r2), u3 = GLD(r3);
    const uint u4 = GLD(r4), u5 = GLD(r5), u6 = GLD(r6), u7 = GLD(r7);
    GACC(r0, u0); GACC(r1, u1); GACC(r2, u2); GACC(r3, u3);
    GACC(r4, u4); GACC(r5, u5); GACC(r6, u6); GACC(r7, u7);
  }
  for (; k < T; k += 4) {
    const int2 r = buf[k];
    const uint u = GLD(r);
    GACC(r, u);
  }
#undef GLD
#undef GACC
  __syncthreads();

  // dense writeout: acc tile -> out rows
  {
    const float4* a4 = (const float4*)acc;
#pragma unroll
    for (int i = t; i < BROWS * 32; i += 256) {
      const int row = i >> 5, q = i & 31;
      const int node = b * BROWS + row;
      if (node < n_nodes) ((float4*)out)[(size_t)node * 32 + q] = a4[i];
    }
  }
}

// ---- drain overflow spill list (expected near-empty; fixed grid for graph) ----
__global__ __launch_bounds__(256) void ovf_scatter(
    const ushort* __restrict__ h, const int* __restrict__ ovf_cnt,
    const int4* __restrict__ ovf, float* __restrict__ out) {
  const int n = min(*ovf_cnt, OVFCAP);
  const int lane = threadIdx.x & 63;
  const int wid = (blockIdx.x * 256 + threadIdx.x) >> 6;
  const int nw = gridDim.x * 4;
  for (int e = wid; e < n; e += nw) {
    int4 rec = ovf[e];
    float v = __int_as_float(rec.z);
    uint u = ((const uint*)(h + (size_t)rec.y * 128))[lane];
    float* op = out + (size_t)rec.x * 128 + lane * 2;
    atomicAdd(op, v * __uint_as_float(u << 16));
    atomicAdd(op + 1, v * __uint_as_float(u & 0xffff0000u));
  }
}

// ---- fallback (small ws): bias init + atomic scatter on bf16 h ----
__global__ __launch_bounds__(256) void init_bias(float* __restrict__ out,
                                                 const float* __restrict__ bias,
                                                 int n4) {
  int i = blockIdx.x * 256 + threadIdx.x;
  if (i < n4) {
    float4 b = ((const float4*)bias)[i & 31];
    ((float4*)out)[i] = b;
  }
}

__global__ __launch_bounds__(256) void scatter_edges(
    const ushort* __restrict__ h, const int* __restrict__ erows,
    const int* __restrict__ ecols, const float* __restrict__ evals,
    float* __restrict__ out, int n_edges) {
  int e = blockIdx.x * 4 + (threadIdx.x >> 6);
  if (e >= n_edges) return;
  int lane = threadIdx.x & 63;
  int row = erows[e];
  int col = ecols[e];
  float v = evals[e];
  uint u = ((const uint*)(h + (size_t)col * 128))[lane];
  float* op = out + (size_t)row * 128 + lane * 2;
  atomicAdd(op, v * __uint_as_float(u << 16));
  atomicAdd(op + 1, v * __uint_as_float(u & 0xffff0000u));
}

extern "C" void kernel_launch(void* const* d_in, const int* in_sizes, int n_in,
                              void* d_out, int out_size, void* d_ws, size_t ws_size,
                              hipStream_t stream) {
  const float* x     = (const float*)d_in[0];
  const int*   erows = (const int*)d_in[1];
  const int*   ecols = (const int*)d_in[2];
  const float* evals = (const float*)d_in[3];
  const float* w     = (const float*)d_in[4];
  const float* bias  = (const float*)d_in[5];
  float* out = (float*)d_out;

  const int n_nodes = in_sizes[0] / 256;
  const int n_edges = in_sizes[1];
  const int nb_buckets = (n_nodes + BROWS - 1) >> BSHIFT;
  const int nb8 = nb_buckets * 8;

  // ws carve-up (256B aligned so bcv regions are line-aligned)
  char* ws = (char*)d_ws;
  size_t off = 0;
  ushort* h  = (ushort*)(ws + off);  off += ((size_t)n_nodes * 128 * 2 + 255) & ~255ull;
  ushort* wt = (ushort*)(ws + off);  off += ((size_t)128 * WT_K * 2 + 255) & ~255ull;
  const size_t cur_ints = (((size_t)nb8) << CSH) + 16;   // + ovf_cnt slot
  int* cursors = (int*)(ws + off);   off += (cur_ints * 4 + 255) & ~255ull;
  int2* bcv    = (int2*)(ws + off);  off += ((size_t)nb8 * CAP * 8 + 255) & ~255ull;
  int4* ovf    = (int4*)(ws + off);  off += (size_t)OVFCAP * 16;
  const bool bucket_ok = (off <= ws_size) && (n_nodes <= (1 << 17));
  int* ovf_cnt = cursors + (((size_t)nb8) << CSH);

  conv_w<<<128, 256, 0, stream>>>(w, wt);
  const int gemm_blocks = (n_nodes + GM_NODES - 1) / GM_NODES;
  gemm_mfma<<<gemm_blocks, 256, 0, stream>>>(x, wt, h, n_nodes);

  if (bucket_ok) {
    hipMemsetAsync(cursors, 0, cur_ints * 4, stream);
    const int eblocks = (n_edges + 1023) / 1024;
    fill_xcd<<<eblocks, 256, 0, stream>>>(erows, ecols, evals, cursors, bcv,
                                          ovf_cnt, ovf, n_edges, nb_buckets);
    gather_acc<<<nb_buckets, 256, 0, stream>>>(h, cursors, bcv, bias, out,
                                               n_nodes, nb_buckets);
    ovf_scatter<<<32, 256, 0, stream>>>(h, ovf_cnt, ovf, out);
  } else {
    const int n4 = out_size / 4;
    init_bias<<<(n4 + 255) / 256, 256, 0, stream>>>(out, bias, n4);
    scatter_edges<<<(n_edges + 3) / 4, 256, 0, stream>>>(h, erows, ecols, evals,
                                                         out, n_edges);
  }
}

// Round 3
// 334.596 us; speedup vs baseline: 4.0982x; 4.0982x over previous
//
#include <hip/hip_runtime.h>

// GCNConv forward: out = segment_sum(vals * (x@W)[cols], rows) + bias
// Round 10: REVERT round-9's gather_acc (fp32 LDS atomicAdd -> CAS retry loop,
// 432 cyc/record, VALU 2.4%). Restore round-8 sort_gather (ownership-based,
// no fp atomics), keep three safe wins:
//  - fill_xcd: 4 edges/thread -> 4 independent load->atomic->store chains
//  - sort_gather: 8-deep gather unroll + dual acc chains (2x MLP, 1/2 chain)
//  - cursor zeroing folded into conv_w (drops the hipMemsetAsync node)
//
// ws: h[N*128] bf16 | wt[128*264] bf16 | cursors[(NB*8)<<4 +16] int |
//     bcv[NB*8*CAP] int2 | ovf[OVFCAP] int4

typedef __attribute__((ext_vector_type(8))) short short8;
typedef __attribute__((ext_vector_type(4))) float floatx4;
typedef __attribute__((ext_vector_type(2))) int intv2;

#define WT_K 264
#define GM_NODES 128
#define BSHIFT 6              // 64 rows per bucket
#define BROWS 64
#define CAP 192               // records per (xcd,bucket) region; mean 128, 5.7 sigma
#define CSH 4                 // counters padded to 16 ints = one 64B line
#define OVFCAP 65536
// s_getreg imm: id=20 (HW_REG_XCC_ID), offset=0, size=4 -> (3<<11)|20
#define XCC_GETREG_IMM 6164

static __device__ __forceinline__ uint f2bf(float x) {  // RNE f32->bf16 bits
  uint u = __float_as_uint(x);
  return (u + 0x7fffu + ((u >> 16) & 1u)) >> 16;
}

// ---- W[k][f] f32 -> wt[f][k] bf16 (k padded to WT_K); also zero cursors ----
__global__ __launch_bounds__(256) void conv_w(const float* __restrict__ w,
                                              ushort* __restrict__ wt,
                                              int* __restrict__ cursors,
                                              int n_ints) {
  const int f = blockIdx.x;
  const int k = threadIdx.x;
  wt[f * WT_K + k] = (ushort)f2bf(w[k * 128 + f]);
  for (int i = blockIdx.x * 256 + threadIdx.x; i < n_ints; i += 128 * 256)
    cursors[i] = 0;
}

// ---- GEMM: h^T = W^T x^T via 16x16x32 bf16 MFMA ----
__global__ __launch_bounds__(256) void gemm_mfma(const float* __restrict__ x,
                                                 const ushort* __restrict__ wt,
                                                 ushort* __restrict__ h,
                                                 int n_nodes) {
  __shared__ ushort lw[128 * WT_K];
  __shared__ ushort xa[GM_NODES * 40];
  const int t = threadIdx.x;
  const int lane = t & 63;
  const int wq = t >> 6;
  const int quad = lane >> 4;
  const int l15 = lane & 15;
  const int row0 = blockIdx.x * GM_NODES;

  {
    const uint4* src = (const uint4*)wt;
    uint4* dst = (uint4*)lw;
    for (int i = t; i < (128 * WT_K * 2) / 16; i += 256) dst[i] = src[i];
  }

  floatx4 acc[2][8];
#pragma unroll
  for (int nt = 0; nt < 2; ++nt)
#pragma unroll
    for (int mt = 0; mt < 8; ++mt) acc[nt][mt] = (floatx4){0.f, 0.f, 0.f, 0.f};

  float4 cur[4];
#pragma unroll
  for (int i = 0; i < 4; ++i) {
    const int idx = i * 256 + t;
    const int row = idx >> 3, kq = idx & 7;
    const int gr = row0 + row;
    cur[i] = (gr < n_nodes) ? *(const float4*)&x[(size_t)gr * 256 + kq * 4]
                            : make_float4(0.f, 0.f, 0.f, 0.f);
  }

  for (int kc = 0; kc < 8; ++kc) {
#pragma unroll
    for (int i = 0; i < 4; ++i) {
      const int idx = i * 256 + t;
      const int row = idx >> 3, kq = idx & 7;
      uint2 p;
      p.x = f2bf(cur[i].x) | (f2bf(cur[i].y) << 16);
      p.y = f2bf(cur[i].z) | (f2bf(cur[i].w) << 16);
      *(uint2*)&xa[row * 40 + kq * 4] = p;
    }
    __syncthreads();

    float4 nxt[4];
    if (kc < 7) {
#pragma unroll
      for (int i = 0; i < 4; ++i) {
        const int idx = i * 256 + t;
        const int row = idx >> 3, kq = idx & 7;
        const int gr = row0 + row;
        nxt[i] = (gr < n_nodes)
                     ? *(const float4*)&x[(size_t)gr * 256 + (kc + 1) * 32 + kq * 4]
                     : make_float4(0.f, 0.f, 0.f, 0.f);
      }
    }

    short8 bfr[2];
    bfr[0] = *(const short8*)&xa[(wq * 32 + l15) * 40 + quad * 8];
    bfr[1] = *(const short8*)&xa[(wq * 32 + 16 + l15) * 40 + quad * 8];
#pragma unroll
    for (int mt = 0; mt < 8; ++mt) {
      const short8 afr =
          *(const short8*)&lw[(mt * 16 + l15) * WT_K + kc * 32 + quad * 8];
      acc[0][mt] = __builtin_amdgcn_mfma_f32_16x16x32_bf16(afr, bfr[0],
                                                           acc[0][mt], 0, 0, 0);
      acc[1][mt] = __builtin_amdgcn_mfma_f32_16x16x32_bf16(afr, bfr[1],
                                                           acc[1][mt], 0, 0, 0);
    }
    __syncthreads();
#pragma unroll
    for (int i = 0; i < 4; ++i) cur[i] = nxt[i];
  }

#pragma unroll
  for (int nt = 0; nt < 2; ++nt) {
    const int node = row0 + wq * 32 + nt * 16 + l15;
    if (node < n_nodes) {
#pragma unroll
      for (int mt = 0; mt < 8; ++mt) {
        uint2 p;
        p.x = f2bf(acc[nt][mt][0]) | (f2bf(acc[nt][mt][1]) << 16);
        p.y = f2bf(acc[nt][mt][2]) | (f2bf(acc[nt][mt][3]) << 16);
        *(uint2*)&h[(size_t)node * 128 + mt * 16 + quad * 4] = p;
      }
    }
  }
}

// ---- append edges into (true-XCD, bucket) regions; rowoff packed in col ----
// XCD-major: region = xcd*nb + bucket -> per-XCD contiguous 2.4MB slab.
// Counters padded to one 64B line each. 4 edges/thread for atomic-latency ILP.
__global__ __launch_bounds__(256) void fill_xcd(
    const int* __restrict__ erows, const int* __restrict__ ecols,
    const float* __restrict__ evals, int* __restrict__ cursors,
    int2* __restrict__ bcv, int* __restrict__ ovf_cnt,
    int4* __restrict__ ovf, int n_edges, int nb) {
  const int base = blockIdx.x * 1024 + threadIdx.x;
  const int xcd = (int)(__builtin_amdgcn_s_getreg(XCC_GETREG_IMM)) & 7;
  int rr[4], cc[4];
  float vv[4];
#pragma unroll
  for (int j = 0; j < 4; ++j) {
    const int i = base + j * 256;
    if (i < n_edges) {
      rr[j] = __builtin_nontemporal_load(&erows[i]);
      cc[j] = __builtin_nontemporal_load(&ecols[i]);
      vv[j] = __builtin_nontemporal_load(&evals[i]);
    }
  }
#pragma unroll
  for (int j = 0; j < 4; ++j) {
    const int i = base + j * 256;
    if (i >= n_edges) continue;
    const int reg = xcd * nb + (rr[j] >> BSHIFT);
    const int pos = atomicAdd(&cursors[reg << CSH], 1);
    if (pos < CAP) {
      int2 p;
      p.x = cc[j] | ((rr[j] & (BROWS - 1)) << 17);
      p.y = __float_as_int(vv[j]);
      bcv[(size_t)reg * CAP + pos] = p;
    } else {
      int op = atomicAdd(ovf_cnt, 1);
      if (op < OVFCAP) {
        int4 q; q.x = rr[j]; q.y = cc[j]; q.z = __float_as_int(vv[j]); q.w = 0;
        ovf[op] = q;
      }
    }
  }
}

// ---- fused per-bucket counting sort (LDS) + node gather ----
// One block per bucket: sort <=1536 records into 12KB LDS, then 4 waves
// gather 16 nodes each (lane = feature pair), write dense out rows + bias.
// No fp atomics anywhere: each row's FMA chain is owned by one wave.
__global__ __launch_bounds__(256) void sort_gather(
    const ushort* __restrict__ h, const int* __restrict__ cursors,
    const int2* __restrict__ bcv, const float* __restrict__ bias,
    float* __restrict__ out, int n_nodes, int nb) {
  __shared__ int2 buf[8 * CAP];            // 12 KB sorted records
  __shared__ int cnt[BROWS], start[BROWS], cur[BROWS];
  __shared__ int scnt[8];
  const int b = blockIdx.x;
  const int t = threadIdx.x;
  if (t < 8) scnt[t] = min(cursors[(t * nb + b) << CSH], CAP);
  if (t < BROWS) cnt[t] = 0;
  __syncthreads();

  // histogram of within-bucket row offsets (native int ds_add)
#pragma unroll
  for (int x = 0; x < 8; ++x) {
    const int n = scnt[x];
    const int2* src = &bcv[(size_t)(x * nb + b) * CAP];
    for (int i = t; i < n; i += 256) atomicAdd(&cnt[((uint)src[i].x) >> 17], 1);
  }
  __syncthreads();

  if (t < BROWS) {   // wave 0: 64-lane inclusive scan -> exclusive starts
    int c = cnt[t];
    int s = c;
#pragma unroll
    for (int off = 1; off < 64; off <<= 1) {
      int u = __shfl_up(s, off, 64);
      if (t >= off) s += u;
    }
    start[t] = s - c;
    cur[t] = s - c;
  }
  __syncthreads();

  // scatter into row-sorted LDS buffer (last use of bcv -> non-temporal)
#pragma unroll
  for (int x = 0; x < 8; ++x) {
    const int n = scnt[x];
    const intv2* src = (const intv2*)&bcv[(size_t)(x * nb + b) * CAP];
    for (int i = t; i < n; i += 256) {
      intv2 rr = __builtin_nontemporal_load(&src[i]);
      int2 rec; rec.x = rr[0]; rec.y = rr[1];
      int pos = atomicAdd(&cur[((uint)rec.x) >> 17], 1);
      buf[pos] = rec;
    }
  }
  __syncthreads();

  // gather: wave w handles rows w*16 .. w*16+15; 8-deep MLP, dual acc chains
  const int lane = t & 63;
  const int w = t >> 6;
  const float2 bv = ((const float2*)bias)[lane];
  for (int rr = w * 16; rr < w * 16 + 16; ++rr) {
    const int node = b * BROWS + rr;
    if (node >= n_nodes) break;
    float2 acca = bv;
    float2 accb = make_float2(0.f, 0.f);
    int p = start[rr];
    const int p1 = start[rr] + cnt[rr];
    for (; p + 8 <= p1; p += 8) {
      int2 e0 = buf[p + 0];
      int2 e1 = buf[p + 1];
      int2 e2 = buf[p + 2];
      int2 e3 = buf[p + 3];
      int2 e4 = buf[p + 4];
      int2 e5 = buf[p + 5];
      int2 e6 = buf[p + 6];
      int2 e7 = buf[p + 7];
      uint u0 = ((const uint*)(h + (size_t)(e0.x & 0x1FFFF) * 128))[lane];
      uint u1 = ((const uint*)(h + (size_t)(e1.x & 0x1FFFF) * 128))[lane];
      uint u2 = ((const uint*)(h + (size_t)(e2.x & 0x1FFFF) * 128))[lane];
      uint u3 = ((const uint*)(h + (size_t)(e3.x & 0x1FFFF) * 128))[lane];
      uint u4 = ((const uint*)(h + (size_t)(e4.x & 0x1FFFF) * 128))[lane];
      uint u5 = ((const uint*)(h + (size_t)(e5.x & 0x1FFFF) * 128))[lane];
      uint u6 = ((const uint*)(h + (size_t)(e6.x & 0x1FFFF) * 128))[lane];
      uint u7 = ((const uint*)(h + (size_t)(e7.x & 0x1FFFF) * 128))[lane];
      float v0 = __int_as_float(e0.y), v1 = __int_as_float(e1.y);
      float v2 = __int_as_float(e2.y), v3 = __int_as_float(e3.y);
      float v4 = __int_as_float(e4.y), v5 = __int_as_float(e5.y);
      float v6 = __int_as_float(e6.y), v7 = __int_as_float(e7.y);
      acca.x += v0 * __uint_as_float(u0 << 16);
      acca.y += v0 * __uint_as_float(u0 & 0xffff0000u);
      accb.x += v1 * __uint_as_float(u1 << 16);
      accb.y += v1 * __uint_as_float(u1 & 0xffff0000u);
      acca.x += v2 * __uint_as_float(u2 << 16);
      acca.y += v2 * __uint_as_float(u2 & 0xffff0000u);
      accb.x += v3 * __uint_as_float(u3 << 16);
      accb.y += v3 * __uint_as_float(u3 & 0xffff0000u);
      acca.x += v4 * __uint_as_float(u4 << 16);
      acca.y += v4 * __uint_as_float(u4 & 0xffff0000u);
      accb.x += v5 * __uint_as_float(u5 << 16);
      accb.y += v5 * __uint_as_float(u5 & 0xffff0000u);
      acca.x += v6 * __uint_as_float(u6 << 16);
      acca.y += v6 * __uint_as_float(u6 & 0xffff0000u);
      accb.x += v7 * __uint_as_float(u7 << 16);
      accb.y += v7 * __uint_as_float(u7 & 0xffff0000u);
    }
    for (; p < p1; ++p) {
      int2 ev = buf[p];
      float v = __int_as_float(ev.y);
      uint u = ((const uint*)(h + (size_t)(ev.x & 0x1FFFF) * 128))[lane];
      acca.x += v * __uint_as_float(u << 16);
      acca.y += v * __uint_as_float(u & 0xffff0000u);
    }
    float2 accf;
    accf.x = acca.x + accb.x;
    accf.y = acca.y + accb.y;
    ((float2*)(out + (size_t)node * 128))[lane] = accf;
  }
}

// ---- drain overflow spill list (expected near-empty; fixed grid for graph) ----
__global__ __launch_bounds__(256) void ovf_scatter(
    const ushort* __restrict__ h, const int* __restrict__ ovf_cnt,
    const int4* __restrict__ ovf, float* __restrict__ out) {
  const int n = min(*ovf_cnt, OVFCAP);
  const int lane = threadIdx.x & 63;
  const int wid = (blockIdx.x * 256 + threadIdx.x) >> 6;
  const int nw = gridDim.x * 4;
  for (int e = wid; e < n; e += nw) {
    int4 rec = ovf[e];
    float v = __int_as_float(rec.z);
    uint u = ((const uint*)(h + (size_t)rec.y * 128))[lane];
    float* op = out + (size_t)rec.x * 128 + lane * 2;
    atomicAdd(op, v * __uint_as_float(u << 16));
    atomicAdd(op + 1, v * __uint_as_float(u & 0xffff0000u));
  }
}

// ---- fallback (small ws): bias init + atomic scatter on bf16 h ----
__global__ __launch_bounds__(256) void init_bias(float* __restrict__ out,
                                                 const float* __restrict__ bias,
                                                 int n4) {
  int i = blockIdx.x * 256 + threadIdx.x;
  if (i < n4) {
    float4 b = ((const float4*)bias)[i & 31];
    ((float4*)out)[i] = b;
  }
}

__global__ __launch_bounds__(256) void scatter_edges(
    const ushort* __restrict__ h, const int* __restrict__ erows,
    const int* __restrict__ ecols, const float* __restrict__ evals,
    float* __restrict__ out, int n_edges) {
  int e = blockIdx.x * 4 + (threadIdx.x >> 6);
  if (e >= n_edges) return;
  int lane = threadIdx.x & 63;
  int row = erows[e];
  int col = ecols[e];
  float v = evals[e];
  uint u = ((const uint*)(h + (size_t)col * 128))[lane];
  float* op = out + (size_t)row * 128 + lane * 2;
  atomicAdd(op, v * __uint_as_float(u << 16));
  atomicAdd(op + 1, v * __uint_as_float(u & 0xffff0000u));
}

extern "C" void kernel_launch(void* const* d_in, const int* in_sizes, int n_in,
                              void* d_out, int out_size, void* d_ws, size_t ws_size,
                              hipStream_t stream) {
  const float* x     = (const float*)d_in[0];
  const int*   erows = (const int*)d_in[1];
  const int*   ecols = (const int*)d_in[2];
  const float* evals = (const float*)d_in[3];
  const float* w     = (const float*)d_in[4];
  const float* bias  = (const float*)d_in[5];
  float* out = (float*)d_out;

  const int n_nodes = in_sizes[0] / 256;
  const int n_edges = in_sizes[1];
  const int nb_buckets = (n_nodes + BROWS - 1) >> BSHIFT;
  const int nb8 = nb_buckets * 8;

  // ws carve-up (256B aligned so bcv regions are line-aligned)
  char* ws = (char*)d_ws;
  size_t off = 0;
  ushort* h  = (ushort*)(ws + off);  off += ((size_t)n_nodes * 128 * 2 + 255) & ~255ull;
  ushort* wt = (ushort*)(ws + off);  off += ((size_t)128 * WT_K * 2 + 255) & ~255ull;
  const size_t cur_ints = (((size_t)nb8) << CSH) + 16;   // + ovf_cnt slot
  int* cursors = (int*)(ws + off);   off += (cur_ints * 4 + 255) & ~255ull;
  int2* bcv    = (int2*)(ws + off);  off += ((size_t)nb8 * CAP * 8 + 255) & ~255ull;
  int4* ovf    = (int4*)(ws + off);  off += (size_t)OVFCAP * 16;
  const bool bucket_ok = (off <= ws_size) && (n_nodes <= (1 << 17));
  int* ovf_cnt = cursors + (((size_t)nb8) << CSH);

  const int zero_ints = bucket_ok ? (int)cur_ints : 0;
  conv_w<<<128, 256, 0, stream>>>(w, wt, cursors, zero_ints);
  const int gemm_blocks = (n_nodes + GM_NODES - 1) / GM_NODES;
  gemm_mfma<<<gemm_blocks, 256, 0, stream>>>(x, wt, h, n_nodes);

  if (bucket_ok) {
    const int eblocks = (n_edges + 1023) / 1024;
    fill_xcd<<<eblocks, 256, 0, stream>>>(erows, ecols, evals, cursors, bcv,
                                          ovf_cnt, ovf, n_edges, nb_buckets);
    sort_gather<<<nb_buckets, 256, 0, stream>>>(h, cursors, bcv, bias, out,
                                                n_nodes, nb_buckets);
    ovf_scatter<<<32, 256, 0, stream>>>(h, ovf_cnt, ovf, out);
  } else {
    const int n4 = out_size / 4;
    init_bias<<<(n4 + 255) / 256, 256, 0, stream>>>(out, bias, n4);
    scatter_edges<<<(n_edges + 3) / 4, 256, 0, stream>>>(h, erows, ecols, evals,
                                                         out, n_edges);
  }
}

// Round 4
// 334.328 us; speedup vs baseline: 4.1015x; 1.0008x over previous
//
#include <hip/hip_runtime.h>

// GCNConv forward: out = segment_sum(vals * (x@W)[cols], rows) + bias
// Round 11: single change vs round 10 — cursor atomics lowered to
// WORKGROUP scope. Evidence: fill_xcd WRITE_SIZE 64MB = 51.2MB (1.6M atomic
// x 32B fabric RMW) + 12.8MB payload, VALU 1.3% -> device-scope atomicAdd
// bypasses the XCD L2 and round-trips the fabric. Our cursors are
// single-XCD by construction (region index includes s_getreg XCC_ID), so a
// workgroup-scope RMW (executes in local TCC, shared by all same-XCD waves)
// is atomic for all accessors. Kernel-boundary release flushes L2 for the
// cross-XCD readers (same mechanism that already passes h between kernels).
// ovf_cnt stays device-scope (any XCD appends).
//
// ws: h[N*128] bf16 | wt[128*264] bf16 | cursors[(NB*8)<<4 +16] int |
//     bcv[NB*8*CAP] int2 | ovf[OVFCAP] int4

typedef __attribute__((ext_vector_type(8))) short short8;
typedef __attribute__((ext_vector_type(4))) float floatx4;
typedef __attribute__((ext_vector_type(2))) int intv2;

#define WT_K 264
#define GM_NODES 128
#define BSHIFT 6              // 64 rows per bucket
#define BROWS 64
#define CAP 192               // records per (xcd,bucket) region; mean 128, 5.7 sigma
#define CSH 4                 // counters padded to 16 ints = one 64B line
#define OVFCAP 65536
// s_getreg imm: id=20 (HW_REG_XCC_ID), offset=0, size=4 -> (3<<11)|20
#define XCC_GETREG_IMM 6164

static __device__ __forceinline__ uint f2bf(float x) {  // RNE f32->bf16 bits
  uint u = __float_as_uint(x);
  return (u + 0x7fffu + ((u >> 16) & 1u)) >> 16;
}

// ---- W[k][f] f32 -> wt[f][k] bf16 (k padded to WT_K); also zero cursors ----
__global__ __launch_bounds__(256) void conv_w(const float* __restrict__ w,
                                              ushort* __restrict__ wt,
                                              int* __restrict__ cursors,
                                              int n_ints) {
  const int f = blockIdx.x;
  const int k = threadIdx.x;
  wt[f * WT_K + k] = (ushort)f2bf(w[k * 128 + f]);
  for (int i = blockIdx.x * 256 + threadIdx.x; i < n_ints; i += 128 * 256)
    cursors[i] = 0;
}

// ---- GEMM: h^T = W^T x^T via 16x16x32 bf16 MFMA ----
__global__ __launch_bounds__(256) void gemm_mfma(const float* __restrict__ x,
                                                 const ushort* __restrict__ wt,
                                                 ushort* __restrict__ h,
                                                 int n_nodes) {
  __shared__ ushort lw[128 * WT_K];
  __shared__ ushort xa[GM_NODES * 40];
  const int t = threadIdx.x;
  const int lane = t & 63;
  const int wq = t >> 6;
  const int quad = lane >> 4;
  const int l15 = lane & 15;
  const int row0 = blockIdx.x * GM_NODES;

  {
    const uint4* src = (const uint4*)wt;
    uint4* dst = (uint4*)lw;
    for (int i = t; i < (128 * WT_K * 2) / 16; i += 256) dst[i] = src[i];
  }

  floatx4 acc[2][8];
#pragma unroll
  for (int nt = 0; nt < 2; ++nt)
#pragma unroll
    for (int mt = 0; mt < 8; ++mt) acc[nt][mt] = (floatx4){0.f, 0.f, 0.f, 0.f};

  float4 cur[4];
#pragma unroll
  for (int i = 0; i < 4; ++i) {
    const int idx = i * 256 + t;
    const int row = idx >> 3, kq = idx & 7;
    const int gr = row0 + row;
    cur[i] = (gr < n_nodes) ? *(const float4*)&x[(size_t)gr * 256 + kq * 4]
                            : make_float4(0.f, 0.f, 0.f, 0.f);
  }

  for (int kc = 0; kc < 8; ++kc) {
#pragma unroll
    for (int i = 0; i < 4; ++i) {
      const int idx = i * 256 + t;
      const int row = idx >> 3, kq = idx & 7;
      uint2 p;
      p.x = f2bf(cur[i].x) | (f2bf(cur[i].y) << 16);
      p.y = f2bf(cur[i].z) | (f2bf(cur[i].w) << 16);
      *(uint2*)&xa[row * 40 + kq * 4] = p;
    }
    __syncthreads();

    float4 nxt[4];
    if (kc < 7) {
#pragma unroll
      for (int i = 0; i < 4; ++i) {
        const int idx = i * 256 + t;
        const int row = idx >> 3, kq = idx & 7;
        const int gr = row0 + row;
        nxt[i] = (gr < n_nodes)
                     ? *(const float4*)&x[(size_t)gr * 256 + (kc + 1) * 32 + kq * 4]
                     : make_float4(0.f, 0.f, 0.f, 0.f);
      }
    }

    short8 bfr[2];
    bfr[0] = *(const short8*)&xa[(wq * 32 + l15) * 40 + quad * 8];
    bfr[1] = *(const short8*)&xa[(wq * 32 + 16 + l15) * 40 + quad * 8];
#pragma unroll
    for (int mt = 0; mt < 8; ++mt) {
      const short8 afr =
          *(const short8*)&lw[(mt * 16 + l15) * WT_K + kc * 32 + quad * 8];
      acc[0][mt] = __builtin_amdgcn_mfma_f32_16x16x32_bf16(afr, bfr[0],
                                                           acc[0][mt], 0, 0, 0);
      acc[1][mt] = __builtin_amdgcn_mfma_f32_16x16x32_bf16(afr, bfr[1],
                                                           acc[1][mt], 0, 0, 0);
    }
    __syncthreads();
#pragma unroll
    for (int i = 0; i < 4; ++i) cur[i] = nxt[i];
  }

#pragma unroll
  for (int nt = 0; nt < 2; ++nt) {
    const int node = row0 + wq * 32 + nt * 16 + l15;
    if (node < n_nodes) {
#pragma unroll
      for (int mt = 0; mt < 8; ++mt) {
        uint2 p;
        p.x = f2bf(acc[nt][mt][0]) | (f2bf(acc[nt][mt][1]) << 16);
        p.y = f2bf(acc[nt][mt][2]) | (f2bf(acc[nt][mt][3]) << 16);
        *(uint2*)&h[(size_t)node * 128 + mt * 16 + quad * 4] = p;
      }
    }
  }
}

// ---- append edges into (true-XCD, bucket) regions; rowoff packed in col ----
// XCD-major: region = xcd*nb + bucket -> per-XCD contiguous 2.4MB slab.
// Counters padded to one 64B line each; cursor atomic is WORKGROUP-scope so
// it executes in the local TCC (all accessors are same-XCD by construction).
__global__ __launch_bounds__(256) void fill_xcd(
    const int* __restrict__ erows, const int* __restrict__ ecols,
    const float* __restrict__ evals, int* __restrict__ cursors,
    int2* __restrict__ bcv, int* __restrict__ ovf_cnt,
    int4* __restrict__ ovf, int n_edges, int nb) {
  const int base = blockIdx.x * 1024 + threadIdx.x;
  const int xcd = (int)(__builtin_amdgcn_s_getreg(XCC_GETREG_IMM)) & 7;
  int rr[4], cc[4];
  float vv[4];
#pragma unroll
  for (int j = 0; j < 4; ++j) {
    const int i = base + j * 256;
    if (i < n_edges) {
      rr[j] = __builtin_nontemporal_load(&erows[i]);
      cc[j] = __builtin_nontemporal_load(&ecols[i]);
      vv[j] = __builtin_nontemporal_load(&evals[i]);
    }
  }
#pragma unroll
  for (int j = 0; j < 4; ++j) {
    const int i = base + j * 256;
    if (i >= n_edges) continue;
    const int reg = xcd * nb + (rr[j] >> BSHIFT);
    const int pos = __hip_atomic_fetch_add(&cursors[reg << CSH], 1,
                                           __ATOMIC_RELAXED,
                                           __HIP_MEMORY_SCOPE_WORKGROUP);
    if (pos < CAP) {
      int2 p;
      p.x = cc[j] | ((rr[j] & (BROWS - 1)) << 17);
      p.y = __float_as_int(vv[j]);
      bcv[(size_t)reg * CAP + pos] = p;
    } else {
      int op = atomicAdd(ovf_cnt, 1);   // device scope: any XCD may append
      if (op < OVFCAP) {
        int4 q; q.x = rr[j]; q.y = cc[j]; q.z = __float_as_int(vv[j]); q.w = 0;
        ovf[op] = q;
      }
    }
  }
}

// ---- fused per-bucket counting sort (LDS) + node gather ----
// One block per bucket: sort <=1536 records into 12KB LDS, then 4 waves
// gather 16 nodes each (lane = feature pair), write dense out rows + bias.
// No fp atomics anywhere: each row's FMA chain is owned by one wave.
__global__ __launch_bounds__(256) void sort_gather(
    const ushort* __restrict__ h, const int* __restrict__ cursors,
    const int2* __restrict__ bcv, const float* __restrict__ bias,
    float* __restrict__ out, int n_nodes, int nb) {
  __shared__ int2 buf[8 * CAP];            // 12 KB sorted records
  __shared__ int cnt[BROWS], start[BROWS], cur[BROWS];
  __shared__ int scnt[8];
  const int b = blockIdx.x;
  const int t = threadIdx.x;
  if (t < 8) scnt[t] = min(cursors[(t * nb + b) << CSH], CAP);
  if (t < BROWS) cnt[t] = 0;
  __syncthreads();

  // histogram of within-bucket row offsets (native int ds_add)
#pragma unroll
  for (int x = 0; x < 8; ++x) {
    const int n = scnt[x];
    const int2* src = &bcv[(size_t)(x * nb + b) * CAP];
    for (int i = t; i < n; i += 256) atomicAdd(&cnt[((uint)src[i].x) >> 17], 1);
  }
  __syncthreads();

  if (t < BROWS) {   // wave 0: 64-lane inclusive scan -> exclusive starts
    int c = cnt[t];
    int s = c;
#pragma unroll
    for (int off = 1; off < 64; off <<= 1) {
      int u = __shfl_up(s, off, 64);
      if (t >= off) s += u;
    }
    start[t] = s - c;
    cur[t] = s - c;
  }
  __syncthreads();

  // scatter into row-sorted LDS buffer (last use of bcv -> non-temporal)
#pragma unroll
  for (int x = 0; x < 8; ++x) {
    const int n = scnt[x];
    const intv2* src = (const intv2*)&bcv[(size_t)(x * nb + b) * CAP];
    for (int i = t; i < n; i += 256) {
      intv2 rr = __builtin_nontemporal_load(&src[i]);
      int2 rec; rec.x = rr[0]; rec.y = rr[1];
      int pos = atomicAdd(&cur[((uint)rec.x) >> 17], 1);
      buf[pos] = rec;
    }
  }
  __syncthreads();

  // gather: wave w handles rows w*16 .. w*16+15; 8-deep MLP, dual acc chains
  const int lane = t & 63;
  const int w = t >> 6;
  const float2 bv = ((const float2*)bias)[lane];
  for (int rr = w * 16; rr < w * 16 + 16; ++rr) {
    const int node = b * BROWS + rr;
    if (node >= n_nodes) break;
    float2 acca = bv;
    float2 accb = make_float2(0.f, 0.f);
    int p = start[rr];
    const int p1 = start[rr] + cnt[rr];
    for (; p + 8 <= p1; p += 8) {
      int2 e0 = buf[p + 0];
      int2 e1 = buf[p + 1];
      int2 e2 = buf[p + 2];
      int2 e3 = buf[p + 3];
      int2 e4 = buf[p + 4];
      int2 e5 = buf[p + 5];
      int2 e6 = buf[p + 6];
      int2 e7 = buf[p + 7];
      uint u0 = ((const uint*)(h + (size_t)(e0.x & 0x1FFFF) * 128))[lane];
      uint u1 = ((const uint*)(h + (size_t)(e1.x & 0x1FFFF) * 128))[lane];
      uint u2 = ((const uint*)(h + (size_t)(e2.x & 0x1FFFF) * 128))[lane];
      uint u3 = ((const uint*)(h + (size_t)(e3.x & 0x1FFFF) * 128))[lane];
      uint u4 = ((const uint*)(h + (size_t)(e4.x & 0x1FFFF) * 128))[lane];
      uint u5 = ((const uint*)(h + (size_t)(e5.x & 0x1FFFF) * 128))[lane];
      uint u6 = ((const uint*)(h + (size_t)(e6.x & 0x1FFFF) * 128))[lane];
      uint u7 = ((const uint*)(h + (size_t)(e7.x & 0x1FFFF) * 128))[lane];
      float v0 = __int_as_float(e0.y), v1 = __int_as_float(e1.y);
      float v2 = __int_as_float(e2.y), v3 = __int_as_float(e3.y);
      float v4 = __int_as_float(e4.y), v5 = __int_as_float(e5.y);
      float v6 = __int_as_float(e6.y), v7 = __int_as_float(e7.y);
      acca.x += v0 * __uint_as_float(u0 << 16);
      acca.y += v0 * __uint_as_float(u0 & 0xffff0000u);
      accb.x += v1 * __uint_as_float(u1 << 16);
      accb.y += v1 * __uint_as_float(u1 & 0xffff0000u);
      acca.x += v2 * __uint_as_float(u2 << 16);
      acca.y += v2 * __uint_as_float(u2 & 0xffff0000u);
      accb.x += v3 * __uint_as_float(u3 << 16);
      accb.y += v3 * __uint_as_float(u3 & 0xffff0000u);
      acca.x += v4 * __uint_as_float(u4 << 16);
      acca.y += v4 * __uint_as_float(u4 & 0xffff0000u);
      accb.x += v5 * __uint_as_float(u5 << 16);
      accb.y += v5 * __uint_as_float(u5 & 0xffff0000u);
      acca.x += v6 * __uint_as_float(u6 << 16);
      acca.y += v6 * __uint_as_float(u6 & 0xffff0000u);
      accb.x += v7 * __uint_as_float(u7 << 16);
      accb.y += v7 * __uint_as_float(u7 & 0xffff0000u);
    }
    for (; p < p1; ++p) {
      int2 ev = buf[p];
      float v = __int_as_float(ev.y);
      uint u = ((const uint*)(h + (size_t)(ev.x & 0x1FFFF) * 128))[lane];
      acca.x += v * __uint_as_float(u << 16);
      acca.y += v * __uint_as_float(u & 0xffff0000u);
    }
    float2 accf;
    accf.x = acca.x + accb.x;
    accf.y = acca.y + accb.y;
    ((float2*)(out + (size_t)node * 128))[lane] = accf;
  }
}

// ---- drain overflow spill list (expected near-empty; fixed grid for graph) ----
__global__ __launch_bounds__(256) void ovf_scatter(
    const ushort* __restrict__ h, const int* __restrict__ ovf_cnt,
    const int4* __restrict__ ovf, float* __restrict__ out) {
  const int n = min(*ovf_cnt, OVFCAP);
  const int lane = threadIdx.x & 63;
  const int wid = (blockIdx.x * 256 + threadIdx.x) >> 6;
  const int nw = gridDim.x * 4;
  for (int e = wid; e < n; e += nw) {
    int4 rec = ovf[e];
    float v = __int_as_float(rec.z);
    uint u = ((const uint*)(h + (size_t)rec.y * 128))[lane];
    float* op = out + (size_t)rec.x * 128 + lane * 2;
    atomicAdd(op, v * __uint_as_float(u << 16));
    atomicAdd(op + 1, v * __uint_as_float(u & 0xffff0000u));
  }
}

// ---- fallback (small ws): bias init + atomic scatter on bf16 h ----
__global__ __launch_bounds__(256) void init_bias(float* __restrict__ out,
                                                 const float* __restrict__ bias,
                                                 int n4) {
  int i = blockIdx.x * 256 + threadIdx.x;
  if (i < n4) {
    float4 b = ((const float4*)bias)[i & 31];
    ((float4*)out)[i] = b;
  }
}

__global__ __launch_bounds__(256) void scatter_edges(
    const ushort* __restrict__ h, const int* __restrict__ erows,
    const int* __restrict__ ecols, const float* __restrict__ evals,
    float* __restrict__ out, int n_edges) {
  int e = blockIdx.x * 4 + (threadIdx.x >> 6);
  if (e >= n_edges) return;
  int lane = threadIdx.x & 63;
  int row = erows[e];
  int col = ecols[e];
  float v = evals[e];
  uint u = ((const uint*)(h + (size_t)col * 128))[lane];
  float* op = out + (size_t)row * 128 + lane * 2;
  atomicAdd(op, v * __uint_as_float(u << 16));
  atomicAdd(op + 1, v * __uint_as_float(u & 0xffff0000u));
}

extern "C" void kernel_launch(void* const* d_in, const int* in_sizes, int n_in,
                              void* d_out, int out_size, void* d_ws, size_t ws_size,
                              hipStream_t stream) {
  const float* x     = (const float*)d_in[0];
  const int*   erows = (const int*)d_in[1];
  const int*   ecols = (const int*)d_in[2];
  const float* evals = (const float*)d_in[3];
  const float* w     = (const float*)d_in[4];
  const float* bias  = (const float*)d_in[5];
  float* out = (float*)d_out;

  const int n_nodes = in_sizes[0] / 256;
  const int n_edges = in_sizes[1];
  const int nb_buckets = (n_nodes + BROWS - 1) >> BSHIFT;
  const int nb8 = nb_buckets * 8;

  // ws carve-up (256B aligned so bcv regions are line-aligned)
  char* ws = (char*)d_ws;
  size_t off = 0;
  ushort* h  = (ushort*)(ws + off);  off += ((size_t)n_nodes * 128 * 2 + 255) & ~255ull;
  ushort* wt = (ushort*)(ws + off);  off += ((size_t)128 * WT_K * 2 + 255) & ~255ull;
  const size_t cur_ints = (((size_t)nb8) << CSH) + 16;   // + ovf_cnt slot
  int* cursors = (int*)(ws + off);   off += (cur_ints * 4 + 255) & ~255ull;
  int2* bcv    = (int2*)(ws + off);  off += ((size_t)nb8 * CAP * 8 + 255) & ~255ull;
  int4* ovf    = (int4*)(ws + off);  off += (size_t)OVFCAP * 16;
  const bool bucket_ok = (off <= ws_size) && (n_nodes <= (1 << 17));
  int* ovf_cnt = cursors + (((size_t)nb8) << CSH);

  const int zero_ints = bucket_ok ? (int)cur_ints : 0;
  conv_w<<<128, 256, 0, stream>>>(w, wt, cursors, zero_ints);
  const int gemm_blocks = (n_nodes + GM_NODES - 1) / GM_NODES;
  gemm_mfma<<<gemm_blocks, 256, 0, stream>>>(x, wt, h, n_nodes);

  if (bucket_ok) {
    const int eblocks = (n_edges + 1023) / 1024;
    fill_xcd<<<eblocks, 256, 0, stream>>>(erows, ecols, evals, cursors, bcv,
                                          ovf_cnt, ovf, n_edges, nb_buckets);
    sort_gather<<<nb_buckets, 256, 0, stream>>>(h, cursors, bcv, bias, out,
                                                n_nodes, nb_buckets);
    ovf_scatter<<<32, 256, 0, stream>>>(h, ovf_cnt, ovf, out);
  } else {
    const int n4 = out_size / 4;
    init_bias<<<(n4 + 255) / 256, 256, 0, stream>>>(out, bias, n4);
    scatter_edges<<<(n_edges + 3) / 4, 256, 0, stream>>>(h, erows, ecols, evals,
                                                         out, n_edges);
  }
}